// Round 4
// baseline (376.961 us; speedup 1.0000x reference)
//
#include <hip/hip_runtime.h>

#pragma clang fp contract(off)

#define NBOX 8192
#define BLK  1024
#define EPT  8
#define NBUCK 2048
#define NB_MAX 256
#define IOU_THR 0.1f

typedef unsigned short u16;
typedef unsigned int u32;
typedef unsigned long long u64;

__global__ void zero_kernel(float4* __restrict__ o, int n4) {
    int i = blockIdx.x * blockDim.x + threadIdx.x;
    if (i < n4) { float4 z; z.x = z.y = z.z = z.w = 0.0f; o[i] = z; }
}

#define SMEM_TOT 98432

__global__ __launch_bounds__(BLK, 4) void nms_kernel(const float* __restrict__ in,
                                                     float* __restrict__ out) {
    __shared__ __align__(16) char smem[SMEM_TOT];
    const int img = blockIdx.x;
    const float* __restrict__ p = in + (size_t)img * 5 * NBOX;
    float* __restrict__ o = out + (size_t)img * 5 * NBOX;
    const int t = threadIdx.x;
    const int lane = t & 63;
    const int wid = t >> 6;

    // ---- LDS overlay map ----
    u64* skey   = (u64*)(smem);             // sort: [0, 65536)
    u32* hist   = (u32*)(smem + 65536);     // sort: 8 KB
    u32* bbase  = (u32*)(smem + 73728);     // sort: 8 KB
    u16* sidx   = (u16*)(smem + 81920);     // persistent: rank -> orig idx, 16 KB
    float4* bx  = (float4*)(smem);          // main: batch boxes, 4 KB
    float4* kx  = (float4*)(smem + 4096);   // main: kept batch boxes, 4 KB
    u64 (*mat)[4] = (u64(*)[4])(smem + 8192); // main: 256x256 bit matrix, 8 KB
    u16* blist  = (u16*)(smem + 16384);     // main: batch slot -> rank, 512 B
    u32* aliveW = (u32*)(smem + 16896);     // main: alive bitmask by rank, 1 KB
    u32* keptW  = (u32*)(smem + 17920);     // main: kept bitmask by rank, 1 KB
    u32* kom    = (u32*)(smem + 18944);     // kept bitmask by orig idx, 1 KB
    u32* pfxA   = (u32*)(smem + 19968);     // output prefix, 1 KB
    int* S0sh   = (int*)(smem + 98304);
    int* nbSh   = (int*)(smem + 98308);
    int* wcnt   = (int*)(smem + 98312);     // 16 ints
    u64* keptQ  = (u64*)(smem + 98376);     // 4 u64

    // ---- init ----
    for (int i = t; i < NBUCK; i += BLK) hist[i] = 0;
    if (t == 0) *S0sh = 0;
    __syncthreads();

    // ---- sort pass 1: bucket + arrival order ----
    u32 mybkt[EPT], myarr[EPT], mykeyhi[EPT];
#pragma unroll
    for (int e = 0; e < EPT; e++) {
        int j = t + e * BLK;
        float s = p[4 * NBOX + j];
        u32 u = __float_as_uint(s);
        u32 ordb = u ^ (u32)(((int)u >> 31) | (int)0x80000000);
        mykeyhi[e] = ~ordb;                       // ascending == score desc
        int vb = (int)(s * (float)NBUCK);
        vb = vb < 0 ? 0 : (vb > NBUCK - 1 ? NBUCK - 1 : vb);
        mybkt[e] = (u32)(NBUCK - 1 - vb);
        myarr[e] = atomicAdd(&hist[mybkt[e]], 1u);
        u64 bal = __ballot(s > 0.0f);
        if (lane == 0) atomicAdd(S0sh, (int)__popcll(bal));
    }
    __syncthreads();

    // ---- exclusive scan over hist (2 bins/thread) ----
    {
        u32 h0 = hist[2 * t], h1 = hist[2 * t + 1];
        int v = (int)(h0 + h1);
        int x = v;
        for (int d = 1; d < 64; d <<= 1) {
            int y = __shfl_up(x, d, 64);
            if (lane >= d) x += y;
        }
        if (lane == 63) wcnt[wid] = x;
        __syncthreads();
        int wb = 0;
        for (int i = 0; i < wid; i++) wb += wcnt[i];
        int excl = wb + x - v;
        bbase[2 * t] = (u32)excl;
        bbase[2 * t + 1] = (u32)excl + h0;
    }
    __syncthreads();

    // ---- scatter keys ----
#pragma unroll
    for (int e = 0; e < EPT; e++) {
        u32 pos = bbase[mybkt[e]] + myarr[e];
        skey[pos] = ((u64)mykeyhi[e] << 32) | (u32)(t + e * BLK);
    }
    __syncthreads();

    // ---- rank within bucket -> sidx ----
#pragma unroll
    for (int e = 0; e < EPT; e++) {
        u32 b = mybkt[e];
        u32 lo = bbase[b], hi2 = lo + hist[b];
        u64 me = ((u64)mykeyhi[e] << 32) | (u32)(t + e * BLK);
        u32 r = lo;
        for (u32 q = lo; q < hi2; q++) r += (skey[q] < me) ? 1u : 0u;
        sidx[r] = (u16)(t + e * BLK);
    }
    __syncthreads();  // skey/hist/bbase now dead; overlay region free

    // ---- init alive/kept/kom bitmasks ----
    int S0 = *S0sh;
    if (t < 256) {
        int lo = t * 32;
        u32 v;
        if (S0 >= lo + 32) v = 0xFFFFFFFFu;
        else if (S0 <= lo) v = 0u;
        else v = (1u << (S0 - lo)) - 1u;
        aliveW[t] = v;
        keptW[t] = 0u;
        kom[t] = 0u;
    }
    __syncthreads();

    // ---- batched greedy loop ----
    while (true) {
        // (A) wave 0: extract first <=256 alive ranks
        if (wid == 0) {
            u32 w[4]; int c[4];
#pragma unroll
            for (int k = 0; k < 4; k++) { w[k] = aliveW[4 * lane + k]; c[k] = __popc(w[k]); }
            int v = c[0] + c[1] + c[2] + c[3];
            int x = v;
            for (int d = 1; d < 64; d <<= 1) {
                int y = __shfl_up(x, d, 64);
                if (lane >= d) x += y;
            }
            int total = __shfl(x, 63, 64);
            int base = x - v;
            if (base < NB_MAX) {
#pragma unroll
                for (int k = 0; k < 4; k++) {
                    u32 ww = w[k];
                    int rbase = (4 * lane + k) << 5;
                    while (ww && base < NB_MAX) {
                        int b = __builtin_ctz(ww); ww &= ww - 1;
                        blist[base++] = (u16)(rbase + b);
                    }
                    if (base >= NB_MAX) break;
                }
            }
            if (lane == 0) *nbSh = total < NB_MAX ? total : NB_MAX;
        }
        __syncthreads();  // B
        int nb = *nbSh;
        if (nb == 0) break;

        // (C) stage batch coords
        if (t < nb) {
            int j = (int)sidx[blist[t]];
            float cx = p[j], cy = p[NBOX + j];
            float w_ = p[2 * NBOX + j], h_ = p[3 * NBOX + j];
            float x1 = cx - w_ * 0.5f, y1 = cy - h_ * 0.5f;
            float x2 = cx + w_ * 0.5f, y2 = cy + h_ * 0.5f;
            bx[t] = make_float4(x1, y1, x2, y2);
        }
        __syncthreads();  // D

        // (E) suppression bit-matrix: row i = t>>2, word seg = t&3
        {
            int i = t >> 2, ws = t & 3;
            if (i < nb) {
                float4 bi = bx[i];
                float ari = (bi.z - bi.x) * (bi.w - bi.y);
                u64 bits = 0;
                int c0 = ws * 64;
                int cmax = nb - c0; if (cmax > 64) cmax = 64;
                for (int cc = 0; cc < cmax; cc++) {
                    int c = c0 + cc;
                    float4 bc = bx[c];
                    float arc = (bc.z - bc.x) * (bc.w - bc.y);
                    float iw = fminf(bi.z, bc.z) - fmaxf(bi.x, bc.x);
                    float ih = fminf(bi.w, bc.w) - fmaxf(bi.y, bc.y);
                    if (c != i && iw > 0.0f && ih > 0.0f) {
                        float inter = iw * ih;
                        float uni = ari + arc - inter;
                        if (inter / (uni + 1e-8f) >= IOU_THR) bits |= (1ull << cc);
                    }
                }
                mat[i][ws] = bits;
            }
        }
        __syncthreads();  // F

        // (G) wave 0: closure resolve (exact greedy on batch)
        if (wid == 0) {
            u64 r0[4], r1[4], r2[4], r3[4];
#pragma unroll
            for (int wq = 0; wq < 4; wq++) {
                r0[wq] = mat[lane][wq];
                r1[wq] = mat[64 + lane][wq];
                r2[wq] = mat[128 + lane][wq];
                r3[wq] = mat[192 + lane][wq];
            }
            u64 A0, A1, A2, A3;
            {
                int n0 = nb;            A0 = n0 <= 0 ? 0ull : (n0 >= 64 ? ~0ull : ((1ull << n0) - 1ull));
                int n1 = nb - 64;       A1 = n1 <= 0 ? 0ull : (n1 >= 64 ? ~0ull : ((1ull << n1) - 1ull));
                int n2 = nb - 128;      A2 = n2 <= 0 ? 0ull : (n2 >= 64 ? ~0ull : ((1ull << n2) - 1ull));
                int n3 = nb - 192;      A3 = n3 <= 0 ? 0ull : (n3 >= 64 ? ~0ull : ((1ull << n3) - 1ull));
            }
            u64 K0 = 0, K1 = 0, K2 = 0, K3 = 0;
            u64 lm = (1ull << lane) - 1ull;
            while (A0 | A1 | A2 | A3) {
                bool c0b = ((A0 >> lane) & 1) && !(r0[0] & A0 & lm);
                bool c1b = ((A1 >> lane) & 1) && !((r1[0] & A0) | (r1[1] & A1 & lm));
                bool c2b = ((A2 >> lane) & 1) && !((r2[0] & A0) | (r2[1] & A1) | (r2[2] & A2 & lm));
                bool c3b = ((A3 >> lane) & 1) && !((r3[0] & A0) | (r3[1] & A1) | (r3[2] & A2) | (r3[3] & A3 & lm));
                u64 C0 = __ballot(c0b), C1 = __ballot(c1b), C2 = __ballot(c2b), C3 = __ballot(c3b);
                K0 |= C0; K1 |= C1; K2 |= C2; K3 |= C3;
                A0 &= ~C0; A1 &= ~C1; A2 &= ~C2; A3 &= ~C3;
                bool s0b = ((A0 >> lane) & 1) && ((r0[0] & C0) | (r0[1] & C1) | (r0[2] & C2) | (r0[3] & C3));
                bool s1b = ((A1 >> lane) & 1) && ((r1[0] & C0) | (r1[1] & C1) | (r1[2] & C2) | (r1[3] & C3));
                bool s2b = ((A2 >> lane) & 1) && ((r2[0] & C0) | (r2[1] & C1) | (r2[2] & C2) | (r2[3] & C3));
                bool s3b = ((A3 >> lane) & 1) && ((r3[0] & C0) | (r3[1] & C1) | (r3[2] & C2) | (r3[3] & C3));
                A0 &= ~__ballot(s0b); A1 &= ~__ballot(s1b); A2 &= ~__ballot(s2b); A3 &= ~__ballot(s3b);
            }
            if (lane < 4) keptQ[lane] = lane == 0 ? K0 : lane == 1 ? K1 : lane == 2 ? K2 : K3;
        }
        __syncthreads();  // H

        // (I) apply batch decisions; compact kept coords
        if (t < NB_MAX && t < nb) {
            int wq = t >> 6;
            u64 kq = keptQ[wq];
            bool isk = (kq >> (t & 63)) & 1;
            int r = blist[t];
            atomicAnd(&aliveW[r >> 5], ~(1u << (r & 31)));
            if (isk) {
                atomicOr(&keptW[r >> 5], 1u << (r & 31));
                int pk = 0;
                for (int q = 0; q < wq; q++) pk += (int)__popcll(keptQ[q]);
                pk += (int)__popcll(kq & ((1ull << (t & 63)) - 1ull));
                kx[pk] = bx[t];
            }
        }
        __syncthreads();  // J
        int nk = (int)(__popcll(keptQ[0]) + __popcll(keptQ[1]) + __popcll(keptQ[2]) + __popcll(keptQ[3]));

        // (K) tail suppression: own 8 static ranks vs kept batch boxes
        {
            u32 aw = aliveW[t >> 2];
            int sh = (t & 3) * 8;
            u32 mybits = (aw >> sh) & 0xFFu;
            u32 killed = 0;
            if (mybits && nk) {
#pragma unroll
                for (int e = 0; e < EPT; e++) {
                    if (mybits & (1u << e)) {
                        int r = t * EPT + e;
                        int j = (int)sidx[r];
                        float cx = p[j], cy = p[NBOX + j];
                        float w_ = p[2 * NBOX + j], h_ = p[3 * NBOX + j];
                        float x1 = cx - w_ * 0.5f, y1 = cy - h_ * 0.5f;
                        float x2 = cx + w_ * 0.5f, y2 = cy + h_ * 0.5f;
                        float ar = (x2 - x1) * (y2 - y1);
                        for (int c = 0; c < nk; c++) {
                            float4 cb = kx[c];
                            float arc = (cb.z - cb.x) * (cb.w - cb.y);
                            float iw = fminf(x2, cb.z) - fmaxf(x1, cb.x);
                            float ih = fminf(y2, cb.w) - fmaxf(y1, cb.y);
                            if (iw > 0.0f && ih > 0.0f) {
                                float inter = iw * ih;
                                float uni = ar + arc - inter;
                                if (inter / (uni + 1e-8f) >= IOU_THR) { killed |= 1u << e; break; }
                            }
                        }
                    }
                }
                if (killed) atomicAnd(&aliveW[t >> 2], ~(killed << sh));
            }
        }
        __syncthreads();  // L
    }

    // ---- map kept-by-rank -> kept-by-original-index ----
    {
        u32 kw = keptW[t >> 2];
        u32 mb = (kw >> ((t & 3) * 8)) & 0xFFu;
        while (mb) {
            int e = __builtin_ctz(mb); mb &= mb - 1;
            int j = (int)sidx[t * EPT + e];
            atomicOr(&kom[j >> 5], 1u << (j & 31));
        }
    }
    __syncthreads();

    // ---- 2-level prefix over kom ----
    {
        u32 w = (t < NBOX / 32) ? kom[t] : 0u;
        int c = __popc(w);
        int x = c;
        for (int d = 1; d < 64; d <<= 1) {
            int y = __shfl_up(x, d, 64);
            if (lane >= d) x += y;
        }
        if (lane == 63) wcnt[wid] = x;
        __syncthreads();
        int wb = 0;
        for (int i = 0; i < wid; i++) wb += wcnt[i];
        if (t < NBOX / 32) pfxA[t] = (u32)(wb + x - c);
    }
    __syncthreads();

    // ---- scatter kept columns (d_out pre-zeroed by zero_kernel) ----
    for (int j = t; j < NBOX; j += BLK) {
        u32 km = kom[j >> 5];
        if ((km >> (j & 31)) & 1u) {
            int pos = (int)(pfxA[j >> 5] + (u32)__popc(km & ((1u << (j & 31)) - 1u)));
            o[0 * NBOX + pos] = p[0 * NBOX + j];
            o[1 * NBOX + pos] = p[1 * NBOX + j];
            o[2 * NBOX + pos] = p[2 * NBOX + j];
            o[3 * NBOX + pos] = p[3 * NBOX + j];
            o[4 * NBOX + pos] = p[4 * NBOX + j];
        }
    }
}

extern "C" void kernel_launch(void* const* d_in, const int* in_sizes, int n_in,
                              void* d_out, int out_size, void* d_ws, size_t ws_size,
                              hipStream_t stream) {
    const float* in = (const float*)d_in[0];
    float* out = (float*)d_out;
    int B = in_sizes[0] / (5 * NBOX);
    int n4 = B * 5 * NBOX / 4;
    hipLaunchKernelGGL(zero_kernel, dim3((n4 + 255) / 256), dim3(256), 0, stream,
                       (float4*)out, n4);
    hipLaunchKernelGGL(nms_kernel, dim3(B), dim3(BLK), 0, stream, in, out);
}

// Round 5
// 198.054 us; speedup vs baseline: 1.9033x; 1.9033x over previous
//
#include <hip/hip_runtime.h>

#pragma clang fp contract(off)

#define NBOX 8192
#define BLK  1024
#define EPT  8
#define NBUCK 2048
#define NB 128
#define IOU_THR 0.1f

typedef unsigned short u16;
typedef unsigned int u32;
typedef unsigned long long u64;

#define SMEM_TOT 151680

__global__ __launch_bounds__(BLK, 4) void nms_kernel(const float* __restrict__ in,
                                                     float* __restrict__ out) {
    __shared__ __align__(16) char smem[SMEM_TOT];
    const int img = blockIdx.x;
    const float* __restrict__ p = in + (size_t)img * 5 * NBOX;
    float* __restrict__ o = out + (size_t)img * 5 * NBOX;
    const int t = threadIdx.x;
    const int lane = t & 63;
    const int wid = t >> 6;

    // persistent LDS
    float4* box   = (float4*)smem;                 // 128 KB: x1,y1,x2,y2 by orig idx
    u16* A        = (u16*)(smem + 131072);         // 16 KB: alive list (orig idx, rank order)
    u64 (*mat)[2] = (u64(*)[2])(smem + 147456);    // 2 KB: 128x128 suppression bits
    u32* kom      = (u32*)(smem + 149504);         // 1 KB: kept bitmask by orig idx
    u32* pfxA     = (u32*)(smem + 150528);         // 1 KB
    int* wcnt     = (int*)(smem + 151552);         // 64 B
    u64* keptSh   = (u64*)(smem + 151616);         // 16 B
    int* S0sh     = (int*)(smem + 151632);
    // sort workspace overlaying box[] (dead after ranking)
    u64* skey  = (u64*)smem;                       // 64 KB
    u32* hist  = (u32*)(smem + 65536);             // 8 KB
    u32* bbase = (u32*)(smem + 73728);             // 8 KB

    // ---- init ----
    for (int i = t; i < NBUCK; i += BLK) hist[i] = 0;
    if (t < 256) kom[t] = 0;
    if (t == 0) *S0sh = 0;
    __syncthreads();

    // ---- sort pass 1: bucket + arrival order ----
    u32 mybkt[EPT], myarr[EPT], mykeyhi[EPT];
#pragma unroll
    for (int e = 0; e < EPT; e++) {
        int j = t + e * BLK;
        float s = p[4 * NBOX + j];
        u32 u = __float_as_uint(s);
        u32 ordb = u ^ (u32)(((int)u >> 31) | (int)0x80000000);
        mykeyhi[e] = ~ordb;                        // ascending == score desc
        int vb = (int)(s * (float)NBUCK);
        vb = vb < 0 ? 0 : (vb > NBUCK - 1 ? NBUCK - 1 : vb);
        mybkt[e] = (u32)(NBUCK - 1 - vb);
        myarr[e] = atomicAdd(&hist[mybkt[e]], 1u);
        u64 bal = __ballot(s > 0.0f);
        if (lane == 0) atomicAdd(S0sh, (int)__popcll(bal));
    }
    __syncthreads();

    // ---- exclusive scan over hist (2 bins/thread) ----
    {
        u32 h0 = hist[2 * t], h1 = hist[2 * t + 1];
        int v = (int)(h0 + h1);
        int x = v;
        for (int d = 1; d < 64; d <<= 1) {
            int y = __shfl_up(x, d, 64);
            if (lane >= d) x += y;
        }
        if (lane == 63) wcnt[wid] = x;
        __syncthreads();
        int wb = 0;
        for (int i = 0; i < wid; i++) wb += wcnt[i];
        int excl = wb + x - v;
        bbase[2 * t] = (u32)excl;
        bbase[2 * t + 1] = (u32)excl + h0;
    }
    __syncthreads();

    // ---- scatter keys ----
#pragma unroll
    for (int e = 0; e < EPT; e++) {
        u32 pos = bbase[mybkt[e]] + myarr[e];
        skey[pos] = ((u64)mykeyhi[e] << 32) | (u32)(t + e * BLK);
    }
    __syncthreads();

    // ---- rank within bucket -> A[rank] = orig idx ----
#pragma unroll
    for (int e = 0; e < EPT; e++) {
        u32 b = mybkt[e];
        u32 lo = bbase[b], hi2 = lo + hist[b];
        u64 me = ((u64)mykeyhi[e] << 32) | (u32)(t + e * BLK);
        u32 r = lo;
        for (u32 q = lo; q < hi2; q++) r += (skey[q] < me) ? 1u : 0u;
        A[r] = (u16)(t + e * BLK);
    }
    int S = 0;
    __syncthreads();   // sort workspace dead after this
    S = *S0sh;

    // ---- fill box[] (coalesced row reads, b128 LDS writes) ----
#pragma unroll
    for (int e = 0; e < EPT; e++) {
        int j = t + e * BLK;
        float cx = p[j], cy = p[NBOX + j];
        float w_ = p[2 * NBOX + j], h_ = p[3 * NBOX + j];
        box[j] = make_float4(cx - w_ * 0.5f, cy - h_ * 0.5f,
                             cx + w_ * 0.5f, cy + h_ * 0.5f);
    }
    __syncthreads();

    // ---- batched greedy loop ----
    while (S > 0) {
        int nb = S < NB ? S : NB;

        // (E) matrix build: wave `wid` computes cols 8*wid..8*wid+7; lane = rows lane, 64+lane
        {
            int r0 = lane, r1 = 64 + lane;
            float4 b0 = box[A[r0]];
            float4 b1 = box[A[r1]];
            float ar0 = (b0.z - b0.x) * (b0.w - b0.y);
            float ar1 = (b1.z - b1.x) * (b1.w - b1.y);
#pragma unroll
            for (int q = 0; q < 8; q++) {
                int c = wid * 8 + q;
                if (c < nb) {
                    float4 cb = box[A[c]];
                    float arc = (cb.z - cb.x) * (cb.w - cb.y);
                    bool s0 = false, s1 = false;
                    if (r0 < nb && r0 != c) {
                        float iw = fminf(b0.z, cb.z) - fmaxf(b0.x, cb.x);
                        float ih = fminf(b0.w, cb.w) - fmaxf(b0.y, cb.y);
                        if (iw > 0.0f && ih > 0.0f) {
                            float inter = iw * ih;
                            float uni = ar0 + arc - inter;
                            s0 = inter / (uni + 1e-8f) >= IOU_THR;
                        }
                    }
                    if (r1 < nb && r1 != c) {
                        float iw = fminf(b1.z, cb.z) - fmaxf(b1.x, cb.x);
                        float ih = fminf(b1.w, cb.w) - fmaxf(b1.y, cb.y);
                        if (iw > 0.0f && ih > 0.0f) {
                            float inter = iw * ih;
                            float uni = ar1 + arc - inter;
                            s1 = inter / (uni + 1e-8f) >= IOU_THR;
                        }
                    }
                    u64 m0 = __ballot(s0);
                    u64 m1 = __ballot(s1);
                    if (lane == 0) { mat[c][0] = m0; mat[c][1] = m1; }
                }
            }
        }
        __syncthreads();

        // (G) closure resolve on wave 0 (exact sequential-greedy equivalence)
        if (wid == 0) {
            u64 rl0 = mat[lane][0],      rl1 = mat[lane][1];
            u64 rh0 = mat[64 + lane][0], rh1 = mat[64 + lane][1];
            u64 A0 = (nb >= 64) ? ~0ull : ((1ull << nb) - 1ull);
            int n1 = nb - 64;
            u64 A1 = n1 <= 0 ? 0ull : (n1 >= 64 ? ~0ull : ((1ull << n1) - 1ull));
            u64 K0 = 0, K1 = 0;
            u64 lm = (1ull << lane) - 1ull;
            while (A0 | A1) {
                bool cl = ((A0 >> lane) & 1) && !(rl0 & A0 & lm);
                bool ch = ((A1 >> lane) & 1) && !((rh0 & A0) | (rh1 & A1 & lm));
                u64 C0 = __ballot(cl), C1 = __ballot(ch);
                K0 |= C0; K1 |= C1;
                A0 &= ~C0; A1 &= ~C1;
                bool sl = ((A0 >> lane) & 1) && ((rl0 & C0) | (rl1 & C1));
                bool sh = ((A1 >> lane) & 1) && ((rh0 & C0) | (rh1 & C1));
                A0 &= ~__ballot(sl);
                A1 &= ~__ballot(sh);
            }
            if (lane == 0) { keptSh[0] = K0; keptSh[1] = K1; }
        }
        __syncthreads();

        u64 k0 = keptSh[0], k1 = keptSh[1];

        // batch apply: record kept orig indices
        if (t < nb) {
            bool isk = (t < 64) ? ((k0 >> t) & 1) : ((k1 >> (t - 64)) & 1);
            if (isk) { int j = (int)A[t]; atomicOr(&kom[j >> 5], 1u << (j & 31)); }
        }

        // (K) tail: contiguous chunk per thread, coords into registers
        int tailN = S - nb;
        int C = (tailN + BLK - 1) / BLK;   // 0..8
        int st = nb + t * C;
        int en = st + C; if (en > S) en = S;
        float4 eb[EPT]; float ea[EPT]; u16 ei[EPT];
        u32 am = 0;
#pragma unroll
        for (int e = 0; e < EPT; e++) {
            int pos = st + e;
            if (e < C && pos < en) {
                u16 j = A[pos];
                ei[e] = j;
                float4 b = box[j];
                eb[e] = b;
                ea[e] = (b.z - b.x) * (b.w - b.y);
                am |= (1u << e);
            }
        }
        // kept-outer walk (uniform broadcast reads), entries inner with mask skip
#pragma unroll
        for (int half = 0; half < 2; half++) {
            u64 kk = half ? k1 : k0;
            int base = half * 64;
            while (kk && am) {
                int s2 = __builtin_ctzll(kk);
                kk &= kk - 1;
                float4 cb = box[A[base + s2]];
                float arc = (cb.z - cb.x) * (cb.w - cb.y);
#pragma unroll
                for (int e = 0; e < EPT; e++) {
                    if (am & (1u << e)) {
                        float iw = fminf(eb[e].z, cb.z) - fmaxf(eb[e].x, cb.x);
                        float ih = fminf(eb[e].w, cb.w) - fmaxf(eb[e].y, cb.y);
                        if (iw > 0.0f && ih > 0.0f) {
                            float inter = iw * ih;
                            float uni = ea[e] + arc - inter;
                            if (inter / (uni + 1e-8f) >= IOU_THR) am &= ~(1u << e);
                        }
                    }
                }
            }
        }

        // compaction: order-preserving block scan + in-place scatter
        {
            int cnt = __popc(am);
            int x = cnt;
            for (int d = 1; d < 64; d <<= 1) {
                int y = __shfl_up(x, d, 64);
                if (lane >= d) x += y;
            }
            if (lane == 63) wcnt[wid] = x;
            __syncthreads();   // all tail reads of A complete before writes
            int wb = 0, tot = 0;
            for (int i = 0; i < BLK / 64; i++) {
                int v = wcnt[i];
                if (i < wid) wb += v;
                tot += v;
            }
            int off = wb + x - cnt;
#pragma unroll
            for (int e = 0; e < EPT; e++) {
                if (am & (1u << e)) A[off++] = ei[e];
            }
            __syncthreads();
            S = tot;
        }
    }
    __syncthreads();

    // ---- output: zero, prefix over kom, scatter kept columns ----
    {
        float4 z; z.x = z.y = z.z = z.w = 0.0f;
        float4* o4 = (float4*)o;
        for (int i = t; i < 5 * NBOX / 4; i += BLK) o4[i] = z;
    }
    {
        u32 w = (t < 256) ? kom[t] : 0u;
        int c = __popc(w);
        int x = c;
        for (int d = 1; d < 64; d <<= 1) {
            int y = __shfl_up(x, d, 64);
            if (lane >= d) x += y;
        }
        if (lane == 63) wcnt[wid] = x;
        __syncthreads();
        int wb = 0;
        for (int i = 0; i < wid; i++) wb += wcnt[i];
        if (t < 256) pfxA[t] = (u32)(wb + x - c);
    }
    __syncthreads();
    for (int j = t; j < NBOX; j += BLK) {
        u32 km = kom[j >> 5];
        if ((km >> (j & 31)) & 1u) {
            int pos = (int)(pfxA[j >> 5] + (u32)__popc(km & ((1u << (j & 31)) - 1u)));
            o[0 * NBOX + pos] = p[0 * NBOX + j];
            o[1 * NBOX + pos] = p[1 * NBOX + j];
            o[2 * NBOX + pos] = p[2 * NBOX + j];
            o[3 * NBOX + pos] = p[3 * NBOX + j];
            o[4 * NBOX + pos] = p[4 * NBOX + j];
        }
    }
}

extern "C" void kernel_launch(void* const* d_in, const int* in_sizes, int n_in,
                              void* d_out, int out_size, void* d_ws, size_t ws_size,
                              hipStream_t stream) {
    const float* in = (const float*)d_in[0];
    float* out = (float*)d_out;
    int B = in_sizes[0] / (5 * NBOX);
    hipLaunchKernelGGL(nms_kernel, dim3(B), dim3(BLK), 0, stream, in, out);
}

// Round 6
// 185.136 us; speedup vs baseline: 2.0361x; 1.0698x over previous
//
#include <hip/hip_runtime.h>

#pragma clang fp contract(off)

#define NBOX 8192
#define BLK  1024
#define EPT  8
#define NBUCK 2048
#define NB 256
#define IOU_THR 0.1f

typedef unsigned short u16;
typedef unsigned int u32;
typedef unsigned long long u64;

#define SMEM_TOT 160896

__global__ __launch_bounds__(BLK, 4) void nms_kernel(const float* __restrict__ in,
                                                     float* __restrict__ out) {
    __shared__ __align__(16) char smem[SMEM_TOT];
    const int img = blockIdx.x;
    const float* __restrict__ p = in + (size_t)img * 5 * NBOX;
    float* __restrict__ o = out + (size_t)img * 5 * NBOX;
    const int t = threadIdx.x;
    const int lane = t & 63;
    const int wid = t >> 6;

    // persistent LDS
    float4* box   = (float4*)smem;                 // 128 KB: x1,y1,x2,y2 by orig idx
    u16* A        = (u16*)(smem + 131072);         // 16 KB: alive list (orig idx, rank order)
    float4* bx    = (float4*)(smem + 147456);      // 4 KB: staged batch coords (compact)
    u64 (*mat)[4] = (u64(*)[4])(smem + 151552);    // 8 KB: 256x256 suppression bits
    float4* kx    = (float4*)(smem + 151552);      // overlay mat rows 0..127: kept coords
    u32* pfxA     = (u32*)(smem + 155648);         // overlay mat rows 128..159 (post-loop)
    u32* kom      = (u32*)(smem + 159744);         // 1 KB: kept bitmask by orig idx
    int* wcnt     = (int*)(smem + 160768);         // 64 B
    u64* keptQ    = (u64*)(smem + 160832);         // 32 B
    int* S0sh     = (int*)(smem + 160864);
    // sort workspace overlaying box[] (dead after ranking)
    u64* skey  = (u64*)smem;                       // 64 KB
    u32* hist  = (u32*)(smem + 65536);             // 8 KB
    u32* bbase = (u32*)(smem + 73728);             // 8 KB

    // ---- init ----
    for (int i = t; i < NBUCK; i += BLK) hist[i] = 0;
    if (t < 256) kom[t] = 0;
    if (t == 0) *S0sh = 0;
    __syncthreads();

    // ---- sort pass 1: bucket + arrival order ----
    u32 mybkt[EPT], myarr[EPT], mykeyhi[EPT];
#pragma unroll
    for (int e = 0; e < EPT; e++) {
        int j = t + e * BLK;
        float s = p[4 * NBOX + j];
        u32 u = __float_as_uint(s);
        u32 ordb = u ^ (u32)(((int)u >> 31) | (int)0x80000000);
        mykeyhi[e] = ~ordb;                        // ascending == score desc
        int vb = (int)(s * (float)NBUCK);
        vb = vb < 0 ? 0 : (vb > NBUCK - 1 ? NBUCK - 1 : vb);
        mybkt[e] = (u32)(NBUCK - 1 - vb);
        myarr[e] = atomicAdd(&hist[mybkt[e]], 1u);
        u64 bal = __ballot(s > 0.0f);
        if (lane == 0) atomicAdd(S0sh, (int)__popcll(bal));
    }
    __syncthreads();

    // ---- exclusive scan over hist (2 bins/thread) ----
    {
        u32 h0 = hist[2 * t], h1 = hist[2 * t + 1];
        int v = (int)(h0 + h1);
        int x = v;
        for (int d = 1; d < 64; d <<= 1) {
            int y = __shfl_up(x, d, 64);
            if (lane >= d) x += y;
        }
        if (lane == 63) wcnt[wid] = x;
        __syncthreads();
        int wb = 0;
        for (int i = 0; i < wid; i++) wb += wcnt[i];
        int excl = wb + x - v;
        bbase[2 * t] = (u32)excl;
        bbase[2 * t + 1] = (u32)excl + h0;
    }
    __syncthreads();

    // ---- scatter keys ----
#pragma unroll
    for (int e = 0; e < EPT; e++) {
        u32 pos = bbase[mybkt[e]] + myarr[e];
        skey[pos] = ((u64)mykeyhi[e] << 32) | (u32)(t + e * BLK);
    }
    __syncthreads();

    // ---- rank within bucket -> A[rank] = orig idx ----
#pragma unroll
    for (int e = 0; e < EPT; e++) {
        u32 b = mybkt[e];
        u32 lo = bbase[b], hi2 = lo + hist[b];
        u64 me = ((u64)mykeyhi[e] << 32) | (u32)(t + e * BLK);
        u32 r = lo;
        for (u32 q = lo; q < hi2; q++) r += (skey[q] < me) ? 1u : 0u;
        A[r] = (u16)(t + e * BLK);
    }
    __syncthreads();   // sort workspace dead after this
    int S = *S0sh;

    // ---- fill box[] (coalesced row reads, b128 LDS writes) ----
#pragma unroll
    for (int e = 0; e < EPT; e++) {
        int j = t + e * BLK;
        float cx = p[j], cy = p[NBOX + j];
        float w_ = p[2 * NBOX + j], h_ = p[3 * NBOX + j];
        box[j] = make_float4(cx - w_ * 0.5f, cy - h_ * 0.5f,
                             cx + w_ * 0.5f, cy + h_ * 0.5f);
    }
    __syncthreads();

    // ---- stage initial batch coords ----
    if (t < NB) bx[t] = box[A[t]];
    __syncthreads();

    // ---- batched greedy loop ----
    while (S > 0) {
        int nb = S < NB ? S : NB;

        // (E) suppression bit-matrix: row i = t>>2, word ws = t&3 (64 tests each)
        {
            int i = t >> 2, ws = t & 3;
            if (i < nb) {
                float4 bi = bx[i];
                float ari = (bi.z - bi.x) * (bi.w - bi.y);
                u64 bits = 0;
                int c0 = ws * 64;
                int cmax = nb - c0; if (cmax > 64) cmax = 64;
                for (int cc = 0; cc < cmax; cc++) {
                    int c = c0 + cc;
                    float4 bc = bx[c];
                    float arc = (bc.z - bc.x) * (bc.w - bc.y);
                    float iw = fminf(bi.z, bc.z) - fmaxf(bi.x, bc.x);
                    float ih = fminf(bi.w, bc.w) - fmaxf(bi.y, bc.y);
                    if (c != i && iw > 0.0f && ih > 0.0f) {
                        float inter = iw * ih;
                        float uni = ari + arc - inter;
                        if (inter / (uni + 1e-8f) >= IOU_THR) bits |= (1ull << cc);
                    }
                }
                mat[i][ws] = bits;
            }
        }
        __syncthreads();  // B1

        // (G) wave 0: closure resolve (exact greedy on batch)
        if (wid == 0) {
            u64 r0[4], r1[4], r2[4], r3[4];
#pragma unroll
            for (int wq = 0; wq < 4; wq++) {
                r0[wq] = mat[lane][wq];
                r1[wq] = mat[64 + lane][wq];
                r2[wq] = mat[128 + lane][wq];
                r3[wq] = mat[192 + lane][wq];
            }
            u64 A0, A1, A2, A3;
            {
                int n0 = nb;       A0 = n0 <= 0 ? 0ull : (n0 >= 64 ? ~0ull : ((1ull << n0) - 1ull));
                int n1 = nb - 64;  A1 = n1 <= 0 ? 0ull : (n1 >= 64 ? ~0ull : ((1ull << n1) - 1ull));
                int n2 = nb - 128; A2 = n2 <= 0 ? 0ull : (n2 >= 64 ? ~0ull : ((1ull << n2) - 1ull));
                int n3 = nb - 192; A3 = n3 <= 0 ? 0ull : (n3 >= 64 ? ~0ull : ((1ull << n3) - 1ull));
            }
            u64 K0 = 0, K1 = 0, K2 = 0, K3 = 0;
            u64 lm = (1ull << lane) - 1ull;
            while (A0 | A1 | A2 | A3) {
                bool c0b = ((A0 >> lane) & 1) && !(r0[0] & A0 & lm);
                bool c1b = ((A1 >> lane) & 1) && !((r1[0] & A0) | (r1[1] & A1 & lm));
                bool c2b = ((A2 >> lane) & 1) && !((r2[0] & A0) | (r2[1] & A1) | (r2[2] & A2 & lm));
                bool c3b = ((A3 >> lane) & 1) && !((r3[0] & A0) | (r3[1] & A1) | (r3[2] & A2) | (r3[3] & A3 & lm));
                u64 C0 = __ballot(c0b), C1 = __ballot(c1b), C2 = __ballot(c2b), C3 = __ballot(c3b);
                K0 |= C0; K1 |= C1; K2 |= C2; K3 |= C3;
                A0 &= ~C0; A1 &= ~C1; A2 &= ~C2; A3 &= ~C3;
                bool s0b = ((A0 >> lane) & 1) && ((r0[0] & C0) | (r0[1] & C1) | (r0[2] & C2) | (r0[3] & C3));
                bool s1b = ((A1 >> lane) & 1) && ((r1[0] & C0) | (r1[1] & C1) | (r1[2] & C2) | (r1[3] & C3));
                bool s2b = ((A2 >> lane) & 1) && ((r2[0] & C0) | (r2[1] & C1) | (r2[2] & C2) | (r2[3] & C3));
                bool s3b = ((A3 >> lane) & 1) && ((r3[0] & C0) | (r3[1] & C1) | (r3[2] & C2) | (r3[3] & C3));
                A0 &= ~__ballot(s0b); A1 &= ~__ballot(s1b); A2 &= ~__ballot(s2b); A3 &= ~__ballot(s3b);
            }
            if (lane < 4) keptQ[lane] = lane == 0 ? K0 : lane == 1 ? K1 : lane == 2 ? K2 : K3;
        }
        __syncthreads();  // B2

        // (I) apply batch decisions (compact kept coords into kx), load tail entries
        u64 kq0 = keptQ[0], kq1 = keptQ[1], kq2 = keptQ[2], kq3 = keptQ[3];
        int nk = (int)(__popcll(kq0) + __popcll(kq1) + __popcll(kq2) + __popcll(kq3));
        if (t < nb) {
            int wq = t >> 6;
            u64 kq = wq == 0 ? kq0 : wq == 1 ? kq1 : wq == 2 ? kq2 : kq3;
            if ((kq >> (t & 63)) & 1) {
                int j = (int)A[t];
                atomicOr(&kom[j >> 5], 1u << (j & 31));
                int pk = 0;
                if (wq > 0) pk += (int)__popcll(kq0);
                if (wq > 1) pk += (int)__popcll(kq1);
                if (wq > 2) pk += (int)__popcll(kq2);
                pk += (int)__popcll(kq & ((1ull << (t & 63)) - 1ull));
                kx[pk] = bx[t];
            }
        }
        int tailN = S - nb;
        int C = (tailN + BLK - 1) / BLK;   // 0..8
        int st = nb + t * C;
        int en = st + C; if (en > S) en = S;
        float4 eb[EPT]; float ea[EPT]; u16 ei[EPT];
        u32 am = 0;
#pragma unroll
        for (int e = 0; e < EPT; e++) {
            int pos = st + e;
            if (e < C && pos < en) {
                u16 j = A[pos];
                ei[e] = j;
                float4 b = box[j];
                eb[e] = b;
                ea[e] = (b.z - b.x) * (b.w - b.y);
                am |= (1u << e);
            }
        }
        __syncthreads();  // B3: kx visible; all A/bx reads done

        // (K) tail suppression: sequential kx walk (pipelined loads, no indirection)
        if (am) {
            for (int c = 0; c < nk; c++) {
                float4 cb = kx[c];
                float arc = (cb.z - cb.x) * (cb.w - cb.y);
#pragma unroll
                for (int e = 0; e < EPT; e++) {
                    if (am & (1u << e)) {
                        float iw = fminf(eb[e].z, cb.z) - fmaxf(eb[e].x, cb.x);
                        float ih = fminf(eb[e].w, cb.w) - fmaxf(eb[e].y, cb.y);
                        if (iw > 0.0f && ih > 0.0f) {
                            float inter = iw * ih;
                            float uni = ea[e] + arc - inter;
                            if (inter / (uni + 1e-8f) >= IOU_THR) am &= ~(1u << e);
                        }
                    }
                }
                if (!am) break;
            }
        }

        // compaction: order-preserving block scan; scatter A (and bx for new batch)
        {
            int cnt = __popc(am);
            int x = cnt;
            for (int d = 1; d < 64; d <<= 1) {
                int y = __shfl_up(x, d, 64);
                if (lane >= d) x += y;
            }
            if (lane == 63) wcnt[wid] = x;
            __syncthreads();  // B4
            int wb = 0, tot = 0;
            for (int i = 0; i < BLK / 64; i++) {
                int v = wcnt[i];
                if (i < wid) wb += v;
                tot += v;
            }
            int off = wb + x - cnt;
#pragma unroll
            for (int e = 0; e < EPT; e++) {
                if (am & (1u << e)) {
                    A[off] = ei[e];
                    if (off < NB) bx[off] = eb[e];
                    off++;
                }
            }
            __syncthreads();  // B5
            S = tot;
        }
    }
    __syncthreads();

    // ---- output: zero, prefix over kom, scatter kept columns ----
    {
        float4 z; z.x = z.y = z.z = z.w = 0.0f;
        float4* o4 = (float4*)o;
        for (int i = t; i < 5 * NBOX / 4; i += BLK) o4[i] = z;
    }
    {
        u32 w = (t < 256) ? kom[t] : 0u;
        int c = __popc(w);
        int x = c;
        for (int d = 1; d < 64; d <<= 1) {
            int y = __shfl_up(x, d, 64);
            if (lane >= d) x += y;
        }
        if (lane == 63) wcnt[wid] = x;
        __syncthreads();
        int wb = 0;
        for (int i = 0; i < wid; i++) wb += wcnt[i];
        if (t < 256) pfxA[t] = (u32)(wb + x - c);
    }
    __syncthreads();
    for (int j = t; j < NBOX; j += BLK) {
        u32 km = kom[j >> 5];
        if ((km >> (j & 31)) & 1u) {
            int pos = (int)(pfxA[j >> 5] + (u32)__popc(km & ((1u << (j & 31)) - 1u)));
            o[0 * NBOX + pos] = p[0 * NBOX + j];
            o[1 * NBOX + pos] = p[1 * NBOX + j];
            o[2 * NBOX + pos] = p[2 * NBOX + j];
            o[3 * NBOX + pos] = p[3 * NBOX + j];
            o[4 * NBOX + pos] = p[4 * NBOX + j];
        }
    }
}

extern "C" void kernel_launch(void* const* d_in, const int* in_sizes, int n_in,
                              void* d_out, int out_size, void* d_ws, size_t ws_size,
                              hipStream_t stream) {
    const float* in = (const float*)d_in[0];
    float* out = (float*)d_out;
    int B = in_sizes[0] / (5 * NBOX);
    hipLaunchKernelGGL(nms_kernel, dim3(B), dim3(BLK), 0, stream, in, out);
}